// Round 6
// baseline (95.121 us; speedup 1.0000x reference)
//
#include <hip/hip_runtime.h>

#ifndef __has_builtin
#define __has_builtin(x) 0
#endif

#if __has_builtin(__builtin_amdgcn_exp2f)
#define FAST_EXP2(x) __builtin_amdgcn_exp2f(x)
#else
#define FAST_EXP2(x) exp2f(x)
#endif
#if __has_builtin(__builtin_amdgcn_rcpf)
#define FAST_RCP(x) __builtin_amdgcn_rcpf(x)
#else
#define FAST_RCP(x) (1.0f / (x))
#endif

#define P_PTS 2048   // points per diagram (problem constant)
#define S_SAMP 128   // samples (problem constant)
#define CHUNK 512    // raw points per block
#define CH 4         // chunks per diagram = P_PTS / CHUNK
#define NTH 256      // threads per block (4 waves)
#define NG 16        // point streams (compacted index mod 16)
#define KS 8         // samples per thread: s = (tid&15) + 16*k

// Kernel 1: one block per (diagram n, chunk ch).
// Phase A: stage + pre-fold (A=2^(-c*y), B=2^(c*x), w); ballot-compact into LDS.
// Phase C: PAIRWISE inner loop -- two compacted points share ONE v_rcp_f32:
//   w1/(1+a) + w2/(1+b) = (w1+w2 + w1*b + w2*a) / (1 + (a+b) + a*b)
//   with a = max(E*A1, B1/E), b = max(E*A2, B2/E)   (max -> min if c<0).
//   Per 2 evals: 12 VALU + 1 trans (was 10 VALU + 2 trans).  Halves the
//   transcendental-pipe demand -- the R4 post-mortem's prime stall suspect.
__global__ __launch_bounds__(NTH, 8) void perslay_part_kernel(
    const float* __restrict__ diagrams,   // (N, P, 2) f32
    const void*  __restrict__ maskp,      // (N, P) bool(byte) or int32 -- autodetected
    const float* __restrict__ samples,    // (S,) f32
    const float* __restrict__ theta,      // (1,)
    const float* __restrict__ constant,   // (1,)
    const float* __restrict__ power,      // (1,)
    float* __restrict__ ws)               // (N*CH, S) f32 partials
{
    __shared__ float4 pts[CHUNK];   // compacted (A, B, w, 0); later aliased as part[]
    __shared__ int    woff[9];      // per-(round,wave) counts -> exclusive prefix

    const int n    = blockIdx.x >> 2;     // diagram
    const int ch   = blockIdx.x & 3;      // chunk within diagram
    const int tid  = threadIdx.x;
    const int lane = tid & 63;
    const int wid  = tid >> 6;            // wave id 0..3

    const float th  = theta[0];
    const float cst = constant[0];
    const float pw  = power[0];
    const float c   = th * 1.4426950408889634f;   // theta * log2(e)

    // Mask dtype autodetect: byte-packed bool with valid-prefix -> word0=0x01010101.
    const unsigned int* mw = (const unsigned int*)maskp;
    const bool isByte = (mw[0] > 1u) | (mw[1] > 1u) | (mw[2] > 1u) | (mw[3] > 1u);

    const size_t pbase_g = (size_t)n * P_PTS + (size_t)ch * CHUNK;
    const float2* __restrict__ dg = ((const float2*)diagrams) + pbase_g;

    // ---- Phase A: stage + compact this chunk's 512 points ------------------
    float4 val[2];
    int    rank[2];
    bool   valid[2];

    #pragma unroll
    for (int r = 0; r < 2; ++r) {
        const int p = r * NTH + tid;
        const float2 xy = dg[p];
        bool m;
        if (isByte) m = ((const unsigned char*)maskp)[pbase_g + p] != 0;
        else        m = ((const int*)maskp)[pbase_g + p] != 0;
        const float pers = xy.y - xy.x;
        const float ap   = fabsf(pers);
        float w;
        if (pw == 1.0f)      w = cst * ap;            // benchmark fast path
        else if (pw == 2.0f) w = cst * ap * ap;
        else                 w = cst * powf(ap, pw);
        valid[r] = m && (w != 0.0f);                  // zero-weight points add exactly 0
        const float A = FAST_EXP2(-c * xy.y);         // 2^(-c*y)
        const float B = FAST_EXP2( c * xy.x);         // 2^(+c*x)
        val[r] = make_float4(A, B, w, 0.0f);
        const unsigned long long b = __ballot(valid[r] ? 1 : 0);
        if (lane == 0) woff[r * 4 + wid] = (int)__popcll(b);
        rank[r] = (int)__popcll(b & ((1ull << lane) - 1ull));
    }
    __syncthreads();

    if (tid == 0) {  // exclusive prefix over the 8 (round,wave) chunks
        int run = 0;
        #pragma unroll
        for (int j = 0; j < 8; ++j) { const int t = woff[j]; woff[j] = run; run += t; }
        woff[8] = run;
    }
    __syncthreads();

    #pragma unroll
    for (int r = 0; r < 2; ++r)
        if (valid[r]) pts[woff[r * 4 + wid] + rank[r]] = val[r];
    const int cnt    = woff[8];
    const int padded = (cnt + 2 * NG - 1) & ~(2 * NG - 1);  // pad to pair rows
    if (tid < padded - cnt) pts[cnt + tid] = make_float4(0.0f, 0.0f, 0.0f, 0.0f);
    __syncthreads();

    // ---- Phase C: pairwise inner sweep -------------------------------------
    const int   g     = tid >> 4;          // stream 0..15
    const int   sbase = tid & 15;          // sample base

    float E[KS], rE[KS], acc[KS];
    #pragma unroll
    for (int k = 0; k < KS; ++k) {
        const float sv = samples[sbase + 16 * k];
        E[k]  = FAST_EXP2( c * sv);        // 2^(+c*s)
        rE[k] = FAST_EXP2(-c * sv);        // 2^(-c*s)
        acc[k] = 0.0f;
    }

    const int jmax = padded >> 5;          // pair-rows: padded / (2*NG)
    const float4* __restrict__ pb = pts + g;

#define INNER_LOOP(SELFN)                                          \
    _Pragma("unroll 2")                                            \
    for (int j = 0; j < jmax; ++j) {                               \
        const float4 v1 = pb[(2 * j)     * NG];                    \
        const float4 v2 = pb[(2 * j + 1) * NG];                    \
        const float w12 = v1.z + v2.z;                             \
        _Pragma("unroll")                                          \
        for (int k = 0; k < KS; ++k) {                             \
            const float a = SELFN(E[k] * v1.x, rE[k] * v1.y);      \
            const float b = SELFN(E[k] * v2.x, rE[k] * v2.y);      \
            const float s = a + b;                                 \
            const float q = fmaf(a, b, s);        /* a+b+ab   */   \
            const float dnm = 1.0f + q;                            \
            const float r = fmaf(v1.z, b, w12);   /* w1*b+w12 */   \
            const float nmr = fmaf(v2.z, a, r);   /* +w2*a    */   \
            acc[k] = fmaf(nmr, FAST_RCP(dnm), acc[k]);             \
        }                                                          \
    }

    if (c >= 0.0f) { INNER_LOOP(fmaxf) } else { INNER_LOOP(fminf) }
#undef INNER_LOOP

    // ---- Reduce 16 streams -> ws[(n*CH+ch), s] -----------------------------
    __syncthreads();                         // all reads of pts done -> safe to alias
    float* part = (float*)pts;               // [NG][S_SAMP] = 8 KB inside pts
    #pragma unroll
    for (int k = 0; k < KS; ++k)
        part[g * S_SAMP + sbase + 16 * k] = acc[k];
    __syncthreads();

    if (tid < S_SAMP) {
        float t = 0.0f;
        #pragma unroll
        for (int gg = 0; gg < NG; ++gg) t += part[gg * S_SAMP + tid];
        ws[(size_t)blockIdx.x * S_SAMP + tid] = t;
    }
}

// Kernel 2: out[n,s] = sum over 4 chunk partials.  Coalesced, trivial.
__global__ __launch_bounds__(256) void perslay_reduce_kernel(
    const float* __restrict__ part,    // (N*CH, S)
    float* __restrict__ out,           // (N, S)
    int total)                         // N*S
{
    const int idx = blockIdx.x * 256 + threadIdx.x;
    if (idx < total) {
        const int n = idx >> 7;
        const int s = idx & (S_SAMP - 1);
        const float* p = part + (size_t)n * CH * S_SAMP + s;
        out[idx] = (p[0] + p[S_SAMP]) + (p[2 * S_SAMP] + p[3 * S_SAMP]);
    }
}

extern "C" void kernel_launch(void* const* d_in, const int* in_sizes, int n_in,
                              void* d_out, int out_size, void* d_ws, size_t ws_size,
                              hipStream_t stream) {
    const float* diagrams = (const float*)d_in[0];
    const void*  mask     = d_in[1];
    const float* samples  = (const float*)d_in[2];
    const float* theta    = (const float*)d_in[3];
    const float* constant = (const float*)d_in[4];
    const float* power    = (const float*)d_in[5];
    float* out = (float*)d_out;
    float* ws  = (float*)d_ws;    // N*CH*S floats = 1 MB, well under ws_size

    const int N = in_sizes[0] / (2 * P_PTS);   // 512
    perslay_part_kernel<<<N * CH, NTH, 0, stream>>>(diagrams, mask, samples,
                                                    theta, constant, power, ws);
    const int total = N * S_SAMP;
    perslay_reduce_kernel<<<(total + 255) / 256, 256, 0, stream>>>(ws, out, total);
}

// Round 8
// 92.971 us; speedup vs baseline: 1.0231x; 1.0231x over previous
//
#include <hip/hip_runtime.h>

#ifndef __has_builtin
#define __has_builtin(x) 0
#endif

#if __has_builtin(__builtin_amdgcn_exp2f)
#define FAST_EXP2(x) __builtin_amdgcn_exp2f(x)
#else
#define FAST_EXP2(x) exp2f(x)
#endif
#if __has_builtin(__builtin_amdgcn_rcpf)
#define FAST_RCP(x) __builtin_amdgcn_rcpf(x)
#else
#define FAST_RCP(x) (1.0f / (x))
#endif

#define P_PTS 2048   // points per diagram (problem constant)
#define S_SAMP 128   // samples (problem constant)
#define CHUNK 512    // raw points per block
#define CH 4         // chunks per diagram = P_PTS / CHUNK
#define NTH 256      // threads per block (4 waves)
#define NG 16        // point streams (compacted index mod 16)
#define KS 8         // samples per thread: s = (tid&15) + 16*k

// Kernel 1: one block per (diagram n, chunk ch).
// Phase A: stage + pre-fold (A=2^(-c*y), B=2^(c*x), w); ballot-compact into LDS.
// Phase C inner loop (R7):
//   - eval slimmed to 4 VALU + 1 trans via  1+max(a,b) = max(1+a, 1+b):
//       t1 = fma(E,A,1); t2 = fma(rE,B,1); u = max(t1,t2); acc += w*rcp(u)
//   - depth-2 register prefetch + unroll-2: two ds_read_b128 in flight per
//     wave, LDS latency hides under the 2x8-eval compute block.
__global__ __launch_bounds__(NTH, 4) void perslay_part_kernel(
    const float* __restrict__ diagrams,   // (N, P, 2) f32
    const void*  __restrict__ maskp,      // (N, P) bool(byte) or int32 -- autodetected
    const float* __restrict__ samples,    // (S,) f32
    const float* __restrict__ theta,      // (1,)
    const float* __restrict__ constant,   // (1,)
    const float* __restrict__ power,      // (1,)
    float* __restrict__ ws)               // (N*CH, S) f32 partials
{
    __shared__ float4 pts[CHUNK + 2 * NG];  // +32: depth-2 prefetch addr stays in-bounds
    __shared__ int    woff[9];              // per-(round,wave) counts -> exclusive prefix

    const int n    = blockIdx.x >> 2;     // diagram
    const int ch   = blockIdx.x & 3;      // chunk within diagram
    const int tid  = threadIdx.x;
    const int lane = tid & 63;
    const int wid  = tid >> 6;            // wave id 0..3

    const float th  = theta[0];
    const float cst = constant[0];
    const float pw  = power[0];
    const float c   = th * 1.4426950408889634f;   // theta * log2(e)

    // Mask dtype autodetect: byte-packed bool with valid-prefix -> word0=0x01010101.
    const unsigned int* mw = (const unsigned int*)maskp;
    const bool isByte = (mw[0] > 1u) | (mw[1] > 1u) | (mw[2] > 1u) | (mw[3] > 1u);

    const size_t pbase_g = (size_t)n * P_PTS + (size_t)ch * CHUNK;
    const float2* __restrict__ dg = ((const float2*)diagrams) + pbase_g;

    // ---- Phase A: stage + compact this chunk's 512 points ------------------
    float4 val[2];
    int    rank[2];
    bool   valid[2];

    #pragma unroll
    for (int r = 0; r < 2; ++r) {
        const int p = r * NTH + tid;
        const float2 xy = dg[p];
        bool m;
        if (isByte) m = ((const unsigned char*)maskp)[pbase_g + p] != 0;
        else        m = ((const int*)maskp)[pbase_g + p] != 0;
        const float pers = xy.y - xy.x;
        const float ap   = fabsf(pers);
        float w;
        if (pw == 1.0f)      w = cst * ap;            // benchmark fast path
        else if (pw == 2.0f) w = cst * ap * ap;
        else                 w = cst * powf(ap, pw);
        valid[r] = m && (w != 0.0f);                  // zero-weight points add exactly 0
        const float A = FAST_EXP2(-c * xy.y);         // 2^(-c*y)
        const float B = FAST_EXP2( c * xy.x);         // 2^(+c*x)
        val[r] = make_float4(A, B, w, 0.0f);
        const unsigned long long b = __ballot(valid[r] ? 1 : 0);
        if (lane == 0) woff[r * 4 + wid] = (int)__popcll(b);
        rank[r] = (int)__popcll(b & ((1ull << lane) - 1ull));
    }
    __syncthreads();

    if (tid == 0) {  // exclusive prefix over the 8 (round,wave) chunks
        int run = 0;
        #pragma unroll
        for (int j = 0; j < 8; ++j) { const int t = woff[j]; woff[j] = run; run += t; }
        woff[8] = run;
    }
    __syncthreads();

    #pragma unroll
    for (int r = 0; r < 2; ++r)
        if (valid[r]) pts[woff[r * 4 + wid] + rank[r]] = val[r];
    const int cnt    = woff[8];
    const int padded = (cnt + 2 * NG - 1) & ~(2 * NG - 1);  // multiple of 32 -> jmax even
    if (tid < padded - cnt) pts[cnt + tid] = make_float4(0.0f, 0.0f, 0.0f, 0.0f);
    __syncthreads();

    // ---- Phase C: software-pipelined inner sweep ---------------------------
    const int   g     = tid >> 4;          // stream 0..15
    const int   sbase = tid & 15;          // sample base

    float E[KS], rE[KS], acc[KS];
    #pragma unroll
    for (int k = 0; k < KS; ++k) {
        const float sv = samples[sbase + 16 * k];
        E[k]  = FAST_EXP2( c * sv);        // 2^(+c*s)
        rE[k] = FAST_EXP2(-c * sv);        // 2^(-c*s)
        acc[k] = 0.0f;
    }

    const int jmax = padded >> 4;          // padded / NG, always even
    const float4* __restrict__ pb = pts + g;

#define EVAL(v, SELFN)                                             \
    _Pragma("unroll")                                              \
    for (int k = 0; k < KS; ++k) {                                 \
        const float t1 = fmaf(E[k],  (v).x, 1.0f);                 \
        const float t2 = fmaf(rE[k], (v).y, 1.0f);                 \
        const float u  = SELFN(t1, t2);                            \
        acc[k] = fmaf((v).z, FAST_RCP(u), acc[k]);                 \
    }

#define INNER_LOOP(SELFN)                                          \
    if (jmax > 0) {                                                \
        float4 b0 = pb[0];                                         \
        float4 b1 = pb[NG];                                        \
        for (int j = 0; j < jmax; j += 2) {                        \
            const float4 n0 = pb[(j + 2) * NG];  /* prefetch */    \
            const float4 n1 = pb[(j + 3) * NG];  /* prefetch */    \
            EVAL(b0, SELFN)                                        \
            EVAL(b1, SELFN)                                        \
            b0 = n0; b1 = n1;                                      \
        }                                                          \
    }

    if (c >= 0.0f) { INNER_LOOP(fmaxf) } else { INNER_LOOP(fminf) }
#undef INNER_LOOP
#undef EVAL

    // ---- Reduce 16 streams -> ws[(n*CH+ch), s] -----------------------------
    __syncthreads();                         // all reads of pts done -> safe to alias
    float* part = (float*)pts;               // [NG][S_SAMP] = 8 KB inside pts
    #pragma unroll
    for (int k = 0; k < KS; ++k)
        part[g * S_SAMP + sbase + 16 * k] = acc[k];
    __syncthreads();

    if (tid < S_SAMP) {
        float t = 0.0f;
        #pragma unroll
        for (int gg = 0; gg < NG; ++gg) t += part[gg * S_SAMP + tid];
        ws[(size_t)blockIdx.x * S_SAMP + tid] = t;
    }
}

// Kernel 2: out[n,s] = sum over 4 chunk partials.  Coalesced, trivial.
__global__ __launch_bounds__(256) void perslay_reduce_kernel(
    const float* __restrict__ part,    // (N*CH, S)
    float* __restrict__ out,           // (N, S)
    int total)                         // N*S
{
    const int idx = blockIdx.x * 256 + threadIdx.x;
    if (idx < total) {
        const int n = idx >> 7;
        const int s = idx & (S_SAMP - 1);
        const float* p = part + (size_t)n * CH * S_SAMP + s;
        out[idx] = (p[0] + p[S_SAMP]) + (p[2 * S_SAMP] + p[3 * S_SAMP]);
    }
}

extern "C" void kernel_launch(void* const* d_in, const int* in_sizes, int n_in,
                              void* d_out, int out_size, void* d_ws, size_t ws_size,
                              hipStream_t stream) {
    const float* diagrams = (const float*)d_in[0];
    const void*  mask     = d_in[1];
    const float* samples  = (const float*)d_in[2];
    const float* theta    = (const float*)d_in[3];
    const float* constant = (const float*)d_in[4];
    const float* power    = (const float*)d_in[5];
    float* out = (float*)d_out;
    float* ws  = (float*)d_ws;    // N*CH*S floats = 1 MB, well under ws_size

    const int N = in_sizes[0] / (2 * P_PTS);   // 512
    perslay_part_kernel<<<N * CH, NTH, 0, stream>>>(diagrams, mask, samples,
                                                    theta, constant, power, ws);
    const int total = N * S_SAMP;
    perslay_reduce_kernel<<<(total + 255) / 256, 256, 0, stream>>>(ws, out, total);
}